// Round 3
// baseline (329.231 us; speedup 1.0000x reference)
//
#include <hip/hip_runtime.h>

typedef float f32x4 __attribute__((ext_vector_type(4)));
typedef short bf16x8 __attribute__((ext_vector_type(8)));
typedef unsigned int u32x4 __attribute__((ext_vector_type(4)));

#define B_TOT 8192
#define D_ 64
#define K_ 16
#define H_ 5
#define IN_ 256

__device__ __forceinline__ unsigned short f2bf(float f){
  unsigned int u = __float_as_uint(f);
  u += 0x7fffu + ((u >> 16) & 1u);   // round-to-nearest-even
  return (unsigned short)(u >> 16);
}

// ---------------- Wpack2: pre-fragmented B for GEMM1 ----------------
// elem[((j*8+kk)*192 + r)*4 + ks][e] = W[r][kk*32+ks*8+e]  (bf16)
// rows r: 0..79 W1(k*5+h), 80..95 Wx, 96..175 sW1, 176..191 sWx
__global__ void pack_weights2_kernel(const float* __restrict__ W1,
                                     const float* __restrict__ Wx,
                                     const float* __restrict__ sW1,
                                     const float* __restrict__ sWx,
                                     unsigned short* __restrict__ Wpack2){
  int j = blockIdx.x, r = blockIdx.y, c = threadIdx.x;
  const float* src;
  if (r < 80)      { int k = r/5, h = r%5;             src = W1  + (((k*D_ + j)*H_ + h)*IN_); }
  else if (r < 96) { int k = r-80;                     src = Wx  + ((k*D_ + j)*IN_); }
  else if (r < 176){ int rr = r-96; int k=rr/5,h=rr%5; src = sW1 + (((k*D_ + j)*H_ + h)*IN_); }
  else             { int k = r-176;                    src = sWx + ((k*D_ + j)*IN_); }
  int kk = c >> 5, ks = (c >> 3) & 3, e = c & 7;
  Wpack2[((((size_t)j*8 + kk)*192 + r)*4 + ks)*8 + e] = f2bf(src[c]);
}

// ---------------- b1pack[j][col 0..191] (f32; 0 on xdot cols) ----------------
__global__ void pack_b1_kernel(const float* __restrict__ b1, const float* __restrict__ sb1,
                               float* __restrict__ b1pack){
  int j = blockIdx.x, r = threadIdx.x;  // 192
  float v = 0.f;
  if (r < 80) v = b1[j*80 + r];
  else if (r >= 96 && r < 176) v = sb1[j*80 + (r-96)];
  b1pack[j*192 + r] = v;
}

// ---------------- B2pack: per-j 8KB blob, row r at byte r*208, 32 rows x 96 cols bf16 ----------------
// rows 0..15: mean Wh block-diag (row k, col k*5+h = Wh[k][j][h]); rows 16..31: sWh
__global__ void pack_b2t_kernel(const float* __restrict__ Wh, const float* __restrict__ sWh,
                                unsigned short* __restrict__ B2pack){
  int j = blockIdx.x, t = threadIdx.x;
  u32x4 z = {0,0,0,0};
  *(u32x4*)((char*)B2pack + (size_t)j*8192 + t*32)      = z;
  *(u32x4*)((char*)B2pack + (size_t)j*8192 + t*32 + 16) = z;
  __syncthreads();
  if (t < 160){
    int half = t / 80, idx = t % 80, k = idx/5, h = idx%5;
    int row = half*16 + k, col = idx;
    const float* W = half ? sWh : Wh;
    unsigned short v = f2bf(W[((size_t)k*D_ + j)*H_ + h]);
    *(unsigned short*)((char*)B2pack + (size_t)j*8192 + row*208 + col*2) = v;
  }
}

// ---------------- masked-softmax target weights: wout[j][i][k] ----------------
__global__ void compute_w_kernel(const float* __restrict__ targets, float* __restrict__ wout){
  int j = blockIdx.x;
  int i = threadIdx.x;
  if (i >= K_) return;
  float base[K_];
  base[0] = (i == 0) ? 1.f : 0.f;
  for (int c = 1; c <= i; ++c)
    base[c] = targets[(j*K_ + i)*(K_-1) + (c-1)] + ((c == i) ? 1.f : 0.f);
  float mx = base[0];
  for (int c = 1; c <= i; ++c) mx = fmaxf(mx, base[c]);
  float e[K_]; float s = 0.f;
  for (int c = 0; c <= i; ++c){ e[c] = expf(base[c] - mx); s += e[c]; }
  float inv = 1.f / s;
  for (int c = 0; c < K_; ++c)
    wout[(j*K_ + i)*K_ + c] = (c <= i) ? e[c]*inv : 0.f;
}

// ---------------- main fused kernel ----------------
// grid (16 jg, 128 bt), 256 thr (4 waves). Per block: 4 j's, 64 rows, 192 cols, K=256.
// LDS: A[64][128]bf16 swz 16384 | G[64][200]bf16 25600 | Gx[64][20]f32 5120 | Gsx 5120 | B2T 8192 | w_l 1024
__global__ __launch_bounds__(256, 2)
void main_kernel(const float* __restrict__ x_values,
                 const float* __restrict__ x_inputs,
                 const unsigned short* __restrict__ Wpack2,
                 const float* __restrict__ wsm,
                 const float* __restrict__ b1pack,
                 const unsigned short* __restrict__ B2pack,
                 const float* __restrict__ b2, const float* __restrict__ sb2,
                 float* __restrict__ partial){
  __shared__ __align__(16) char sm[61440];
  unsigned short* G = (unsigned short*)(sm + 16384); // [64][200]
  float* Gx  = (float*)(sm + 41984);                 // [64][20]
  float* Gsx = (float*)(sm + 47104);                 // [64][20]
  char*  B2T = sm + 52224;                           // 32 rows * 208B (8KB region)
  float* w_l = (float*)(sm + 60416);                 // [16][16]

  const int t   = threadIdx.x;
  const int lane = t & 63, wv = t >> 6;
  const int l15 = lane & 15, lg = lane >> 4;
  const int jg = blockIdx.x, b0 = blockIdx.y * 64;

  f32x4 acc1[4][3];
  f32x4 acc3 = {0.f,0.f,0.f,0.f};
  bf16x8 bfr[2][12];
  f32x4 aA[8];
  u32x4 b2tR0, b2tR1;

  // ================= prologue: stage step 0 =================
  b2tR0 = *(const u32x4*)((const char*)B2pack + (size_t)(jg*4)*8192 + t*32);
  b2tR1 = *(const u32x4*)((const char*)B2pack + (size_t)(jg*4)*8192 + t*32 + 16);
  {
    const int jN = jg*4;
    const float* ap = x_inputs + ((size_t)(b0 + (t>>4))*D_ + jN)*IN_ + (t&15)*8;
    #pragma unroll
    for (int p = 0; p < 4; ++p){
      aA[p*2]   = *(const f32x4*)(ap + (size_t)p*16*D_*IN_);
      aA[p*2+1] = *(const f32x4*)(ap + (size_t)p*16*D_*IN_ + 4);
    }
    #pragma unroll
    for (int kkl = 0; kkl < 4; ++kkl)
      #pragma unroll
      for (int n = 0; n < 3; ++n){
        const int o = wv*48 + n*16 + l15;
        bfr[0][kkl*3+n] = *(const bf16x8*)(Wpack2 + ((((size_t)jN*8 + kkl)*192 + o)*4 + lg)*8);
      }
    // cvt + write A(0) [round-1-verified swizzled layout]
    #pragma unroll
    for (int p = 0; p < 4; ++p){
      const int row = p*16 + (t>>4);
      bf16x8 o;
      o[0]=f2bf(aA[p*2][0]);   o[1]=f2bf(aA[p*2][1]);   o[2]=f2bf(aA[p*2][2]);   o[3]=f2bf(aA[p*2][3]);
      o[4]=f2bf(aA[p*2+1][0]); o[5]=f2bf(aA[p*2+1][1]); o[6]=f2bf(aA[p*2+1][2]); o[7]=f2bf(aA[p*2+1][3]);
      *(bf16x8*)(sm + row*256 + (((t&15)*16) ^ ((row & 7) << 4))) = o;
    }
  }
  __syncthreads();

  // ================= 8 steps: s = jj*2 + kc =================
  #pragma unroll
  for (int s = 0; s < 8; ++s){
    const int jj = s >> 1, kc = s & 1, cur = s & 1;
    const int j = jg*4 + jj;

    // (0) kc==0: commit B2T + w_l for this jj
    if (kc == 0){
      *(u32x4*)(B2T + t*32)      = b2tR0;
      *(u32x4*)(B2T + t*32 + 16) = b2tR1;
      w_l[t] = wsm[(j << 8) + t];
      #pragma unroll
      for (int m = 0; m < 4; ++m)
        #pragma unroll
        for (int n = 0; n < 3; ++n) acc1[m][n] = (f32x4){0.f,0.f,0.f,0.f};
    }

    // (1) prefetch issues for step s+1
    if (s < 7){
      const int sn = s+1, jjN = sn>>1, kcN = sn&1, jN = jg*4 + jjN;
      const float* ap = x_inputs + ((size_t)(b0 + (t>>4))*D_ + jN)*IN_ + kcN*128 + (t&15)*8;
      #pragma unroll
      for (int p = 0; p < 4; ++p){
        aA[p*2]   = *(const f32x4*)(ap + (size_t)p*16*D_*IN_);
        aA[p*2+1] = *(const f32x4*)(ap + (size_t)p*16*D_*IN_ + 4);
      }
      #pragma unroll
      for (int kkl = 0; kkl < 4; ++kkl)
        #pragma unroll
        for (int n = 0; n < 3; ++n){
          const int o = wv*48 + n*16 + l15;
          bfr[sn&1][kkl*3+n] = *(const bf16x8*)(Wpack2 + ((((size_t)jN*8 + kcN*4 + kkl)*192 + o)*4 + lg)*8);
        }
      if (kcN == 0){
        b2tR0 = *(const u32x4*)((const char*)B2pack + (size_t)jN*8192 + t*32);
        b2tR1 = *(const u32x4*)((const char*)B2pack + (size_t)jN*8192 + t*32 + 16);
      }
    }

    // (2) MFMA1 on A-buf + bfr[cur]
    #pragma unroll
    for (int kkl = 0; kkl < 4; ++kkl){
      bf16x8 af[4];
      #pragma unroll
      for (int m = 0; m < 4; ++m){
        const int row = m*16 + l15;
        af[m] = *(const bf16x8*)(sm + row*256 + ((kkl*64 + lg*16) ^ ((row & 7) << 4)));
      }
      #pragma unroll
      for (int m = 0; m < 4; ++m)
        #pragma unroll
        for (int n = 0; n < 3; ++n)
          acc1[m][n] = __builtin_amdgcn_mfma_f32_16x16x32_bf16(af[m], bfr[cur][kkl*3+n], acc1[m][n], 0, 0, 0);
    }

    // (3) A-buf consumed by all waves
    __syncthreads();

    // (4) cvt + write A(s+1)
    if (s < 7){
      #pragma unroll
      for (int p = 0; p < 4; ++p){
        const int row = p*16 + (t>>4);
        bf16x8 o;
        o[0]=f2bf(aA[p*2][0]);   o[1]=f2bf(aA[p*2][1]);   o[2]=f2bf(aA[p*2][2]);   o[3]=f2bf(aA[p*2][3]);
        o[4]=f2bf(aA[p*2+1][0]); o[5]=f2bf(aA[p*2+1][1]); o[6]=f2bf(aA[p*2+1][2]); o[7]=f2bf(aA[p*2+1][3]);
        *(bf16x8*)(sm + row*256 + (((t&15)*16) ^ ((row & 7) << 4))) = o;
      }
    }

    // (5) kc==1: epilogue for jj
    if (kc == 1){
      // ---- G write (lrelu+b1 fused; xdot cols -> f32 side buffers, bf16 zeros into G) ----
      #pragma unroll
      for (int n = 0; n < 3; ++n){
        const int col = wv*48 + n*16 + l15;
        const bool isx  = (col >= 80 && col < 96);
        const bool issx = (col >= 176);
        const float b1v = (isx || issx) ? 0.f : b1pack[j*192 + col];
        #pragma unroll
        for (int m = 0; m < 4; ++m){
          const int row = m*16 + lg*4;
          if (isx){
            #pragma unroll
            for (int e = 0; e < 4; ++e){
              Gx[(row+e)*20 + (col-80)] = acc1[m][n][e];
              G[(row+e)*200 + col] = 0;   // defined zeros for MFMA2 (B2T col is zero there)
            }
          } else if (issx){
            #pragma unroll
            for (int e = 0; e < 4; ++e){
              Gsx[(row+e)*20 + (col-176)] = acc1[m][n][e];
              G[(row+e)*200 + col] = 0;
            }
          } else {
            #pragma unroll
            for (int e = 0; e < 4; ++e){
              float v = acc1[m][n][e] + b1v;
              v = fmaxf(v, 0.2f*v);
              G[(row+e)*200 + col] = f2bf(v);
            }
          }
        }
      }
      __syncthreads();

      // ---- MFMA2: D[k][b] = B2T * G^T, C = xdot + bias ----
      const int brow = wv*16 + l15;
      f32x4 accm = *(const f32x4*)(Gx  + brow*20 + lg*4) + *(const f32x4*)(b2  + j*16 + lg*4);
      f32x4 accs = *(const f32x4*)(Gsx + brow*20 + lg*4) + *(const f32x4*)(sb2 + j*16 + lg*4);
      #pragma unroll
      for (int kk = 0; kk < 3; ++kk){
        bf16x8 a0 = *(const bf16x8*)(B2T + l15*208      + kk*64 + lg*16);
        bf16x8 a1 = *(const bf16x8*)(B2T + (16+l15)*208 + kk*64 + lg*16);
        bf16x8 g0 = *(const bf16x8*)((char*)G + brow*400       + kk*64 + lg*16);
        bf16x8 g1 = *(const bf16x8*)((char*)G + brow*400 + 192 + kk*64 + lg*16);
        accm = __builtin_amdgcn_mfma_f32_16x16x32_bf16(a0, g0, accm, 0, 0, 0);
        accs = __builtin_amdgcn_mfma_f32_16x16x32_bf16(a1, g1, accs, 0, 0, 0);
      }

      // ---- E1: nll nodes (lane holds k = lg*4+e for row brow) ----
      const float xv = x_values[(size_t)(b0 + brow)*D_ + j];
      float nn4[4];
      #pragma unroll
      for (int e = 0; e < 4; ++e){
        float mean = accm[e];
        float shv  = accs[e];
        float ex = __expf(-shv);
        float sg = __fdividef(10.f, 1.f + ex);
        float var = fmaxf(sg*sg, 1e-6f);
        float d = xv - mean;
        nn4[e] = 0.5f*(__logf(var) + __fdividef(d*d, var));
      }

      // ---- E2: acc3[q] += sum_k w[j][i][k]*nll[k][b],  i = lg*4+q ----
      #pragma unroll
      for (int g = 0; g < 4; ++g){
        float v0 = nn4[0], v1 = nn4[1], v2 = nn4[2], v3 = nn4[3];
        if (g){
          v0 = __shfl_xor(v0, g<<4); v1 = __shfl_xor(v1, g<<4);
          v2 = __shfl_xor(v2, g<<4); v3 = __shfl_xor(v3, g<<4);
        }
        const int kb = ((lg ^ g) << 2);
        #pragma unroll
        for (int q = 0; q < 4; ++q){
          f32x4 wq = *(const f32x4*)(w_l + (lg*4+q)*16 + kb);
          acc3[q] += wq[0]*v0 + wq[1]*v1 + wq[2]*v2 + wq[3]*v3;
        }
      }
    }

    // (6) end-of-step barrier
    __syncthreads();
  }

  // final store: partial[jg][b][i], lane covers i = lg*4..lg*4+3 for b = b0+wv*16+l15
  *(f32x4*)(partial + ((size_t)jg*B_TOT + b0 + wv*16 + l15)*16 + lg*4) = acc3;
}

// ---------------- final reduce over 16 j-groups ----------------
__global__ void reduce_kernel(const float* __restrict__ partial, float* __restrict__ out){
  int idx = blockIdx.x*256 + threadIdx.x;   // 131072
  float s = 0.f;
  #pragma unroll
  for (int g = 0; g < 16; ++g) s += partial[(size_t)g*(B_TOT*K_) + idx];
  out[idx] = s;
}

extern "C" void kernel_launch(void* const* d_in, const int* in_sizes, int n_in,
                              void* d_out, int out_size, void* d_ws, size_t ws_size,
                              hipStream_t stream){
  const float* x_values = (const float*)d_in[0];
  const float* x_inputs = (const float*)d_in[1];
  const float* targets  = (const float*)d_in[2];
  const float* W1  = (const float*)d_in[3];
  const float* b1  = (const float*)d_in[4];
  const float* Wh  = (const float*)d_in[5];
  const float* Wx  = (const float*)d_in[6];
  const float* b2  = (const float*)d_in[7];
  const float* sW1 = (const float*)d_in[8];
  const float* sb1 = (const float*)d_in[9];
  const float* sWh = (const float*)d_in[10];
  const float* sWx = (const float*)d_in[11];
  const float* sb2 = (const float*)d_in[12];
  (void)in_sizes; (void)n_in; (void)out_size; (void)ws_size;

  char* ws = (char*)d_ws;
  unsigned short* Wpack2 = (unsigned short*)ws;          // 6,291,456
  float* wsm     = (float*)(ws + 6291456);               // 65,536
  float* b1pack  = (float*)(ws + 6356992);               // 49,152
  unsigned short* B2pack = (unsigned short*)(ws + 6406144); // 524,288
  float* partial = (float*)(ws + 6930432);               // 8,388,608
  float* out = (float*)d_out;

  pack_weights2_kernel<<<dim3(64, 192), 256, 0, stream>>>(W1, Wx, sW1, sWx, Wpack2);
  pack_b1_kernel<<<dim3(64), 192, 0, stream>>>(b1, sb1, b1pack);
  pack_b2t_kernel<<<dim3(64), 256, 0, stream>>>(Wh, sWh, B2pack);
  compute_w_kernel<<<dim3(64), 64, 0, stream>>>(targets, wsm);
  main_kernel<<<dim3(16, 128), 256, 0, stream>>>(x_values, x_inputs, Wpack2, wsm,
                                                 b1pack, B2pack, b2, sb2, partial);
  reduce_kernel<<<dim3(512), 256, 0, stream>>>(partial, out);
}

// Round 4
// 294.512 us; speedup vs baseline: 1.1179x; 1.1179x over previous
//
#include <hip/hip_runtime.h>

typedef float f32x4 __attribute__((ext_vector_type(4)));
typedef short bf16x8 __attribute__((ext_vector_type(8)));
typedef unsigned int u32x4 __attribute__((ext_vector_type(4)));

#define B_TOT 8192
#define D_ 64
#define K_ 16
#define H_ 5
#define IN_ 256

__device__ __forceinline__ unsigned short f2bf(float f){
  unsigned int u = __float_as_uint(f);
  u += 0x7fffu + ((u >> 16) & 1u);   // round-to-nearest-even
  return (unsigned short)(u >> 16);
}

__device__ __forceinline__ unsigned int cvtpk(float lo, float hi){
  unsigned int r;
  asm("v_cvt_pk_bf16_f32 %0, %1, %2" : "=v"(r) : "v"(lo), "v"(hi));
  return r;
}

// ---------------- Wpack2: pre-fragmented B for GEMM1 ----------------
// elem[((j*8+kk)*192 + r)*4 + ks][e] = W[r][kk*32+ks*8+e]  (bf16)
// rows r: 0..79 W1(k*5+h), 80..95 Wx, 96..175 sW1, 176..191 sWx
__global__ void pack_weights2_kernel(const float* __restrict__ W1,
                                     const float* __restrict__ Wx,
                                     const float* __restrict__ sW1,
                                     const float* __restrict__ sWx,
                                     unsigned short* __restrict__ Wpack2){
  int j = blockIdx.x, r = blockIdx.y, c = threadIdx.x;
  const float* src;
  if (r < 80)      { int k = r/5, h = r%5;             src = W1  + (((k*D_ + j)*H_ + h)*IN_); }
  else if (r < 96) { int k = r-80;                     src = Wx  + ((k*D_ + j)*IN_); }
  else if (r < 176){ int rr = r-96; int k=rr/5,h=rr%5; src = sW1 + (((k*D_ + j)*H_ + h)*IN_); }
  else             { int k = r-176;                    src = sWx + ((k*D_ + j)*IN_); }
  int kk = c >> 5, ks = (c >> 3) & 3, e = c & 7;
  Wpack2[((((size_t)j*8 + kk)*192 + r)*4 + ks)*8 + e] = f2bf(src[c]);
}

// ---------------- b1pack[j][col 0..191] (f32; 0 on xdot cols) ----------------
__global__ void pack_b1_kernel(const float* __restrict__ b1, const float* __restrict__ sb1,
                               float* __restrict__ b1pack){
  int j = blockIdx.x, r = threadIdx.x;  // 192
  float v = 0.f;
  if (r < 80) v = b1[j*80 + r];
  else if (r >= 96 && r < 176) v = sb1[j*80 + (r-96)];
  b1pack[j*192 + r] = v;
}

// ---------------- B2pack: per-j 8KB blob, row r at byte r*208, 32 rows x 96 cols bf16 ----------------
// rows 0..15: mean Wh block-diag (row k, col k*5+h = Wh[k][j][h]); rows 16..31: sWh
__global__ void pack_b2t_kernel(const float* __restrict__ Wh, const float* __restrict__ sWh,
                                unsigned short* __restrict__ B2pack){
  int j = blockIdx.x, t = threadIdx.x;
  u32x4 z = {0,0,0,0};
  *(u32x4*)((char*)B2pack + (size_t)j*8192 + t*32)      = z;
  *(u32x4*)((char*)B2pack + (size_t)j*8192 + t*32 + 16) = z;
  __syncthreads();
  if (t < 160){
    int half = t / 80, idx = t % 80, k = idx/5, h = idx%5;
    int row = half*16 + k, col = idx;
    const float* W = half ? sWh : Wh;
    unsigned short v = f2bf(W[((size_t)k*D_ + j)*H_ + h]);
    *(unsigned short*)((char*)B2pack + (size_t)j*8192 + row*208 + col*2) = v;
  }
}

// ---------------- masked-softmax target weights: wout[j][i][k] ----------------
__global__ void compute_w_kernel(const float* __restrict__ targets, float* __restrict__ wout){
  int j = blockIdx.x;
  int i = threadIdx.x;
  if (i >= K_) return;
  float base[K_];
  base[0] = (i == 0) ? 1.f : 0.f;
  for (int c = 1; c <= i; ++c)
    base[c] = targets[(j*K_ + i)*(K_-1) + (c-1)] + ((c == i) ? 1.f : 0.f);
  float mx = base[0];
  for (int c = 1; c <= i; ++c) mx = fmaxf(mx, base[c]);
  float e[K_]; float s = 0.f;
  for (int c = 0; c <= i; ++c){ e[c] = expf(base[c] - mx); s += e[c]; }
  float inv = 1.f / s;
  for (int c = 0; c < K_; ++c)
    wout[(j*K_ + i)*K_ + c] = (c <= i) ? e[c]*inv : 0.f;
}

// ---------------- main fused kernel ----------------
// grid (16 jg, 128 bt), 256 thr (4 waves). Per block: 4 j's, 64 rows, 192 cols, K=256.
// LDS: A[64][128]bf16 swz 16384 | G[64][200]bf16 25600 | Gx[64][20]f32 5120 | Gsx 5120 | B2T 8192 | w_l 1024
__global__ __launch_bounds__(256, 2)
void main_kernel(const float* __restrict__ x_values,
                 const float* __restrict__ x_inputs,
                 const unsigned short* __restrict__ Wpack2,
                 const float* __restrict__ wsm,
                 const float* __restrict__ b1pack,
                 const unsigned short* __restrict__ B2pack,
                 const float* __restrict__ b2, const float* __restrict__ sb2,
                 float* __restrict__ partial){
  __shared__ __align__(16) char sm[61440];
  unsigned short* G = (unsigned short*)(sm + 16384); // [64][200]
  float* Gx  = (float*)(sm + 41984);                 // [64][20]
  float* Gsx = (float*)(sm + 47104);                 // [64][20]
  char*  B2T = sm + 52224;                           // 32 rows * 208B (8KB region)
  float* w_l = (float*)(sm + 60416);                 // [16][16]

  const int t   = threadIdx.x;
  const int lane = t & 63, wv = t >> 6;
  const int l15 = lane & 15, lg = lane >> 4;
  const int jg = blockIdx.x, b0 = blockIdx.y * 64;

  f32x4 acc1[4][3];
  f32x4 acc3 = {0.f,0.f,0.f,0.f};
  bf16x8 bfr[12];          // single-buffered B fragments (−48 VGPR vs round 3)
  f32x4 aA[8];
  u32x4 b2tR0, b2tR1;

  // ================= prologue: stage A(0) =================
  b2tR0 = *(const u32x4*)((const char*)B2pack + (size_t)(jg*4)*8192 + t*32);
  b2tR1 = *(const u32x4*)((const char*)B2pack + (size_t)(jg*4)*8192 + t*32 + 16);
  {
    const float* ap = x_inputs + ((size_t)(b0 + (t>>4))*D_ + jg*4)*IN_ + (t&15)*8;
    #pragma unroll
    for (int p = 0; p < 4; ++p){
      aA[p*2]   = *(const f32x4*)(ap + (size_t)p*16*D_*IN_);
      aA[p*2+1] = *(const f32x4*)(ap + (size_t)p*16*D_*IN_ + 4);
    }
    #pragma unroll
    for (int p = 0; p < 4; ++p){
      const int row = p*16 + (t>>4);
      u32x4 o;
      o[0] = cvtpk(aA[p*2][0],   aA[p*2][1]);
      o[1] = cvtpk(aA[p*2][2],   aA[p*2][3]);
      o[2] = cvtpk(aA[p*2+1][0], aA[p*2+1][1]);
      o[3] = cvtpk(aA[p*2+1][2], aA[p*2+1][3]);
      *(u32x4*)(sm + row*256 + (((t&15)*16) ^ ((row & 7) << 4))) = o;
    }
  }
  __syncthreads();

  // ================= 8 steps: s = jj*2 + kc =================
  #pragma unroll
  for (int s = 0; s < 8; ++s){
    const int jj = s >> 1, kc = s & 1;
    const int j = jg*4 + jj;

    // (1a) B fragments for THIS step (latency hides under setup + other waves)
    #pragma unroll
    for (int kkl = 0; kkl < 4; ++kkl)
      #pragma unroll
      for (int n = 0; n < 3; ++n){
        const int o = wv*48 + n*16 + l15;
        bfr[kkl*3+n] = *(const bf16x8*)(Wpack2 + ((((size_t)j*8 + kc*4 + kkl)*192 + o)*4 + lg)*8);
      }

    // (0) kc==0: commit B2T + w_l for this jj
    if (kc == 0){
      *(u32x4*)(B2T + t*32)      = b2tR0;
      *(u32x4*)(B2T + t*32 + 16) = b2tR1;
      w_l[t] = wsm[(j << 8) + t];
      #pragma unroll
      for (int m = 0; m < 4; ++m)
        #pragma unroll
        for (int n = 0; n < 3; ++n) acc1[m][n] = (f32x4){0.f,0.f,0.f,0.f};
    }

    // (1b) prefetch A for step s+1 (+ B2T regs at j boundary)
    if (s < 7){
      const int sn = s+1, jjN = sn>>1, kcN = sn&1, jN = jg*4 + jjN;
      const float* ap = x_inputs + ((size_t)(b0 + (t>>4))*D_ + jN)*IN_ + kcN*128 + (t&15)*8;
      #pragma unroll
      for (int p = 0; p < 4; ++p){
        aA[p*2]   = *(const f32x4*)(ap + (size_t)p*16*D_*IN_);
        aA[p*2+1] = *(const f32x4*)(ap + (size_t)p*16*D_*IN_ + 4);
      }
      if (kcN == 0){
        b2tR0 = *(const u32x4*)((const char*)B2pack + (size_t)jN*8192 + t*32);
        b2tR1 = *(const u32x4*)((const char*)B2pack + (size_t)jN*8192 + t*32 + 16);
      }
    }

    // (2) MFMA1 on A-buf + bfr
    #pragma unroll
    for (int kkl = 0; kkl < 4; ++kkl){
      bf16x8 af[4];
      #pragma unroll
      for (int m = 0; m < 4; ++m){
        const int row = m*16 + l15;
        af[m] = *(const bf16x8*)(sm + row*256 + ((kkl*64 + lg*16) ^ ((row & 7) << 4)));
      }
      #pragma unroll
      for (int m = 0; m < 4; ++m)
        #pragma unroll
        for (int n = 0; n < 3; ++n)
          acc1[m][n] = __builtin_amdgcn_mfma_f32_16x16x32_bf16(af[m], bfr[kkl*3+n], acc1[m][n], 0, 0, 0);
    }

    // (3) A-buf consumed by all waves
    __syncthreads();

    // (4) cvt + write A(s+1)
    if (s < 7){
      #pragma unroll
      for (int p = 0; p < 4; ++p){
        const int row = p*16 + (t>>4);
        u32x4 o;
        o[0] = cvtpk(aA[p*2][0],   aA[p*2][1]);
        o[1] = cvtpk(aA[p*2][2],   aA[p*2][3]);
        o[2] = cvtpk(aA[p*2+1][0], aA[p*2+1][1]);
        o[3] = cvtpk(aA[p*2+1][2], aA[p*2+1][3]);
        *(u32x4*)(sm + row*256 + (((t&15)*16) ^ ((row & 7) << 4))) = o;
      }
    }

    // (5) kc==1: epilogue for jj
    if (kc == 1){
      // ---- G write (lrelu+b1 fused; xdot cols -> f32 side buffers, bf16 zeros into G) ----
      #pragma unroll
      for (int n = 0; n < 3; ++n){
        const int col = wv*48 + n*16 + l15;
        const bool isx  = (col >= 80 && col < 96);
        const bool issx = (col >= 176);
        const float b1v = (isx || issx) ? 0.f : b1pack[j*192 + col];
        #pragma unroll
        for (int m = 0; m < 4; ++m){
          const int row = m*16 + lg*4;
          if (isx){
            #pragma unroll
            for (int e = 0; e < 4; ++e){
              Gx[(row+e)*20 + (col-80)] = acc1[m][n][e];
              G[(row+e)*200 + col] = 0;   // defined zeros for MFMA2 (B2T col is zero there)
            }
          } else if (issx){
            #pragma unroll
            for (int e = 0; e < 4; ++e){
              Gsx[(row+e)*20 + (col-176)] = acc1[m][n][e];
              G[(row+e)*200 + col] = 0;
            }
          } else {
            #pragma unroll
            for (int e = 0; e < 4; ++e){
              float v = acc1[m][n][e] + b1v;
              v = fmaxf(v, 0.2f*v);
              G[(row+e)*200 + col] = f2bf(v);
            }
          }
        }
      }
      __syncthreads();

      // ---- MFMA2: D[k][b] = B2T * G^T, C = xdot + bias ----
      const int brow = wv*16 + l15;
      f32x4 accm = *(const f32x4*)(Gx  + brow*20 + lg*4) + *(const f32x4*)(b2  + j*16 + lg*4);
      f32x4 accs = *(const f32x4*)(Gsx + brow*20 + lg*4) + *(const f32x4*)(sb2 + j*16 + lg*4);
      #pragma unroll
      for (int kk = 0; kk < 3; ++kk){
        bf16x8 a0 = *(const bf16x8*)(B2T + l15*208      + kk*64 + lg*16);
        bf16x8 a1 = *(const bf16x8*)(B2T + (16+l15)*208 + kk*64 + lg*16);
        bf16x8 g0 = *(const bf16x8*)((char*)G + brow*400       + kk*64 + lg*16);
        bf16x8 g1 = *(const bf16x8*)((char*)G + brow*400 + 192 + kk*64 + lg*16);
        accm = __builtin_amdgcn_mfma_f32_16x16x32_bf16(a0, g0, accm, 0, 0, 0);
        accs = __builtin_amdgcn_mfma_f32_16x16x32_bf16(a1, g1, accs, 0, 0, 0);
      }

      // ---- E1: nll nodes (lane holds k = lg*4+e for row brow) ----
      const float xv = x_values[(size_t)(b0 + brow)*D_ + j];
      float nn4[4];
      #pragma unroll
      for (int e = 0; e < 4; ++e){
        float mean = accm[e];
        float shv  = accs[e];
        float ex = __expf(-shv);
        float sg = __fdividef(10.f, 1.f + ex);
        float var = fmaxf(sg*sg, 1e-6f);
        float d = xv - mean;
        nn4[e] = 0.5f*(__logf(var) + __fdividef(d*d, var));
      }

      // ---- E2: acc3[q] += sum_k w[j][i][k]*nll[k][b],  i = lg*4+q ----
      #pragma unroll
      for (int g = 0; g < 4; ++g){
        float v0 = nn4[0], v1 = nn4[1], v2 = nn4[2], v3 = nn4[3];
        if (g){
          v0 = __shfl_xor(v0, g<<4); v1 = __shfl_xor(v1, g<<4);
          v2 = __shfl_xor(v2, g<<4); v3 = __shfl_xor(v3, g<<4);
        }
        const int kb = ((lg ^ g) << 2);
        #pragma unroll
        for (int q = 0; q < 4; ++q){
          f32x4 wq = *(const f32x4*)(w_l + (lg*4+q)*16 + kb);
          acc3[q] += wq[0]*v0 + wq[1]*v1 + wq[2]*v2 + wq[3]*v3;
        }
      }
    }

    // (6) end-of-step barrier
    __syncthreads();
  }

  // final store: partial[jg][b][i], lane covers i = lg*4..lg*4+3 for b = b0+wv*16+l15
  *(f32x4*)(partial + ((size_t)jg*B_TOT + b0 + wv*16 + l15)*16 + lg*4) = acc3;
}

// ---------------- final reduce over 16 j-groups ----------------
__global__ void reduce_kernel(const float* __restrict__ partial, float* __restrict__ out){
  int idx = blockIdx.x*256 + threadIdx.x;   // 131072
  float s = 0.f;
  #pragma unroll
  for (int g = 0; g < 16; ++g) s += partial[(size_t)g*(B_TOT*K_) + idx];
  out[idx] = s;
}

extern "C" void kernel_launch(void* const* d_in, const int* in_sizes, int n_in,
                              void* d_out, int out_size, void* d_ws, size_t ws_size,
                              hipStream_t stream){
  const float* x_values = (const float*)d_in[0];
  const float* x_inputs = (const float*)d_in[1];
  const float* targets  = (const float*)d_in[2];
  const float* W1  = (const float*)d_in[3];
  const float* b1  = (const float*)d_in[4];
  const float* Wh  = (const float*)d_in[5];
  const float* Wx  = (const float*)d_in[6];
  const float* b2  = (const float*)d_in[7];
  const float* sW1 = (const float*)d_in[8];
  const float* sb1 = (const float*)d_in[9];
  const float* sWh = (const float*)d_in[10];
  const float* sWx = (const float*)d_in[11];
  const float* sb2 = (const float*)d_in[12];
  (void)in_sizes; (void)n_in; (void)out_size; (void)ws_size;

  char* ws = (char*)d_ws;
  unsigned short* Wpack2 = (unsigned short*)ws;          // 6,291,456
  float* wsm     = (float*)(ws + 6291456);               // 65,536
  float* b1pack  = (float*)(ws + 6356992);               // 49,152
  unsigned short* B2pack = (unsigned short*)(ws + 6406144); // 524,288
  float* partial = (float*)(ws + 6930432);               // 8,388,608
  float* out = (float*)d_out;

  pack_weights2_kernel<<<dim3(64, 192), 256, 0, stream>>>(W1, Wx, sW1, sWx, Wpack2);
  pack_b1_kernel<<<dim3(64), 192, 0, stream>>>(b1, sb1, b1pack);
  pack_b2t_kernel<<<dim3(64), 256, 0, stream>>>(Wh, sWh, B2pack);
  compute_w_kernel<<<dim3(64), 64, 0, stream>>>(targets, wsm);
  main_kernel<<<dim3(16, 128), 256, 0, stream>>>(x_values, x_inputs, Wpack2, wsm,
                                                 b1pack, B2pack, b2, sb2, partial);
  reduce_kernel<<<dim3(512), 256, 0, stream>>>(partial, out);
}

// Round 5
// 242.800 us; speedup vs baseline: 1.3560x; 1.2130x over previous
//
#include <hip/hip_runtime.h>

typedef float f32x4 __attribute__((ext_vector_type(4)));
typedef short bf16x8 __attribute__((ext_vector_type(8)));
typedef unsigned int u32x4 __attribute__((ext_vector_type(4)));

#define B_TOT 8192
#define D_ 64
#define K_ 16
#define H_ 5
#define IN_ 256

__device__ __forceinline__ unsigned short f2bf(float f){
  unsigned int u = __float_as_uint(f);
  u += 0x7fffu + ((u >> 16) & 1u);   // round-to-nearest-even
  return (unsigned short)(u >> 16);
}

__device__ __forceinline__ unsigned int cvtpk(float lo, float hi){
  unsigned int r;
  asm("v_cvt_pk_bf16_f32 %0, %1, %2" : "=v"(r) : "v"(lo), "v"(hi));
  return r;
}

// ---------------- Wpack2: pre-fragmented B for GEMM1 ----------------
// elem[((j*8+kk)*192 + r)*4 + ks][e] = W[r][kk*32+ks*8+e]  (bf16)
// rows r: 0..79 W1(k*5+h), 80..95 Wx, 96..175 sW1, 176..191 sWx
__global__ void pack_weights2_kernel(const float* __restrict__ W1,
                                     const float* __restrict__ Wx,
                                     const float* __restrict__ sW1,
                                     const float* __restrict__ sWx,
                                     unsigned short* __restrict__ Wpack2){
  int j = blockIdx.x, r = blockIdx.y, c = threadIdx.x;
  const float* src;
  if (r < 80)      { int k = r/5, h = r%5;             src = W1  + (((k*D_ + j)*H_ + h)*IN_); }
  else if (r < 96) { int k = r-80;                     src = Wx  + ((k*D_ + j)*IN_); }
  else if (r < 176){ int rr = r-96; int k=rr/5,h=rr%5; src = sW1 + (((k*D_ + j)*H_ + h)*IN_); }
  else             { int k = r-176;                    src = sWx + ((k*D_ + j)*IN_); }
  int kk = c >> 5, ks = (c >> 3) & 3, e = c & 7;
  Wpack2[((((size_t)j*8 + kk)*192 + r)*4 + ks)*8 + e] = f2bf(src[c]);
}

// ---------------- b1pack[j][col 0..191] (f32; 0 on xdot cols) ----------------
__global__ void pack_b1_kernel(const float* __restrict__ b1, const float* __restrict__ sb1,
                               float* __restrict__ b1pack){
  int j = blockIdx.x, r = threadIdx.x;  // 192
  float v = 0.f;
  if (r < 80) v = b1[j*80 + r];
  else if (r >= 96 && r < 176) v = sb1[j*80 + (r-96)];
  b1pack[j*192 + r] = v;
}

// ---------------- B2packF: MFMA2 A-operand fragments, reg-resident in main ----------------
// B2packF[(j*3+kk)*1024 + r*32 + lg*8 + e] = W2T[r][kk*32+lg*8+e]
// W2T[r][c]: r<16 -> Wh[k=r][j][h=c-5k] if 0<=c-5k<5 else 0; r>=16 -> sWh[k=r-16]
__global__ void pack_b2f_kernel(const float* __restrict__ Wh, const float* __restrict__ sWh,
                                unsigned short* __restrict__ B2packF){
  int j = blockIdx.x, kk = blockIdx.y, t = threadIdx.x;  // 256 thr, 1024 elems
  #pragma unroll
  for (int q = 0; q < 4; ++q){
    int f = t*4 + q;                 // r*32 + lg*8 + e
    int e = f & 7, lg = (f >> 3) & 3, r = f >> 5;
    int c = kk*32 + lg*8 + e;        // 0..95
    int k = r & 15;
    int h = c - 5*k;
    float v = 0.f;
    if (h >= 0 && h < 5) v = (r < 16 ? Wh : sWh)[((size_t)k*D_ + j)*H_ + h];
    B2packF[((size_t)j*3 + kk)*1024 + f] = f2bf(v);
  }
}

// ---------------- masked-softmax target weights: wout[j][i][k] ----------------
__global__ void compute_w_kernel(const float* __restrict__ targets, float* __restrict__ wout){
  int j = blockIdx.x;
  int i = threadIdx.x;
  if (i >= K_) return;
  float base[K_];
  base[0] = (i == 0) ? 1.f : 0.f;
  for (int c = 1; c <= i; ++c)
    base[c] = targets[(j*K_ + i)*(K_-1) + (c-1)] + ((c == i) ? 1.f : 0.f);
  float mx = base[0];
  for (int c = 1; c <= i; ++c) mx = fmaxf(mx, base[c]);
  float e[K_]; float s = 0.f;
  for (int c = 0; c <= i; ++c){ e[c] = expf(base[c] - mx); s += e[c]; }
  float inv = 1.f / s;
  for (int c = 0; c < K_; ++c)
    wout[(j*K_ + i)*K_ + c] = (c <= i) ? e[c]*inv : 0.f;
}

// ---------------- main fused kernel ----------------
// grid (16 jg, 128 bt), 256 thr (4 waves), 3 blocks/CU. Per block: 4 j's, 64 rows, 192 cols.
// LDS 52 KB: A[64][128]bf16 swz 16384 | G[64][200]bf16 25600 | Gx[64][20]f32 5120 | Gsx 5120 | w_l 1024
__global__ __launch_bounds__(256, 3)
void main_kernel(const float* __restrict__ x_values,
                 const float* __restrict__ x_inputs,
                 const unsigned short* __restrict__ Wpack2,
                 const float* __restrict__ wsm,
                 const float* __restrict__ b1pack,
                 const unsigned short* __restrict__ B2packF,
                 const float* __restrict__ b2, const float* __restrict__ sb2,
                 float* __restrict__ partial){
  __shared__ __align__(16) char sm[53248];
  unsigned short* G = (unsigned short*)(sm + 16384); // [64][200]
  float* Gx  = (float*)(sm + 41984);                 // [64][20]
  float* Gsx = (float*)(sm + 47104);                 // [64][20]
  float* w_l = (float*)(sm + 52224);                 // [16][16]

  const int t   = threadIdx.x;
  const int lane = t & 63, wv = t >> 6;
  const int l15 = lane & 15, lg = lane >> 4;
  const int jg = blockIdx.x, b0 = blockIdx.y * 64;

  f32x4 acc1[4][3];
  f32x4 acc3 = {0.f,0.f,0.f,0.f};
  bf16x8 bfr[12];     // GEMM1 B fragments, single-buffered
  bf16x8 b2tf[6];     // MFMA2 A fragments (per j)

  for (int jj = 0; jj < 4; ++jj){
    const int j = jg*4 + jj;

    // ---- issue B fragments (kc0), MFMA2 fragments, w_l; then stage A(kc0) ----
    #pragma unroll
    for (int kkl = 0; kkl < 4; ++kkl)
      #pragma unroll
      for (int n = 0; n < 3; ++n){
        const int o = wv*48 + n*16 + l15;
        bfr[kkl*3+n] = *(const bf16x8*)(Wpack2 + ((((size_t)j*8 + kkl)*192 + o)*4 + lg)*8);
      }
    #pragma unroll
    for (int kk = 0; kk < 3; ++kk){
      b2tf[kk]   = *(const bf16x8*)(B2packF + ((size_t)j*3 + kk)*1024 + l15*32 + lg*8);
      b2tf[3+kk] = *(const bf16x8*)(B2packF + ((size_t)j*3 + kk)*1024 + (16+l15)*32 + lg*8);
    }
    w_l[t] = wsm[(j << 8) + t];

    // stage A chunk kc=0 (2 passes of 4 f32x4 -> cvt -> 2 ds_write_b128)
    {
      const int r0 = t >> 4, cb = t & 15;
      const float* ap = x_inputs + ((size_t)(b0 + r0)*D_ + j)*IN_ + cb*8;
      #pragma unroll
      for (int pp = 0; pp < 2; ++pp){
        f32x4 v[4];
        #pragma unroll
        for (int p = 0; p < 2; ++p){
          v[p*2]   = *(const f32x4*)(ap + (size_t)(pp*2+p)*16*D_*IN_);
          v[p*2+1] = *(const f32x4*)(ap + (size_t)(pp*2+p)*16*D_*IN_ + 4);
        }
        #pragma unroll
        for (int p = 0; p < 2; ++p){
          const int row = (pp*2+p)*16 + r0;
          u32x4 o;
          o[0] = cvtpk(v[p*2][0],   v[p*2][1]);
          o[1] = cvtpk(v[p*2][2],   v[p*2][3]);
          o[2] = cvtpk(v[p*2+1][0], v[p*2+1][1]);
          o[3] = cvtpk(v[p*2+1][2], v[p*2+1][3]);
          *(u32x4*)(sm + row*256 + ((cb*16) ^ ((row & 7) << 4))) = o;
        }
      }
    }
    #pragma unroll
    for (int m = 0; m < 4; ++m)
      #pragma unroll
      for (int n = 0; n < 3; ++n) acc1[m][n] = (f32x4){0.f,0.f,0.f,0.f};
    __syncthreads();                                   // B1: A0 + w_l ready

    // ---- MFMA1 kc=0 ----
    #pragma unroll
    for (int kkl = 0; kkl < 4; ++kkl){
      bf16x8 af[4];
      #pragma unroll
      for (int m = 0; m < 4; ++m){
        const int row = m*16 + l15;
        af[m] = *(const bf16x8*)(sm + row*256 + ((kkl*64 + lg*16) ^ ((row & 7) << 4)));
      }
      #pragma unroll
      for (int m = 0; m < 4; ++m)
        #pragma unroll
        for (int n = 0; n < 3; ++n)
          acc1[m][n] = __builtin_amdgcn_mfma_f32_16x16x32_bf16(af[m], bfr[kkl*3+n], acc1[m][n], 0, 0, 0);
    }

    // issue B fragments (kc1) — overlap with barrier + stage A(kc1)
    #pragma unroll
    for (int kkl = 0; kkl < 4; ++kkl)
      #pragma unroll
      for (int n = 0; n < 3; ++n){
        const int o = wv*48 + n*16 + l15;
        bfr[kkl*3+n] = *(const bf16x8*)(Wpack2 + ((((size_t)j*8 + 4 + kkl)*192 + o)*4 + lg)*8);
      }
    __syncthreads();                                   // B2: A0 consumed by all

    // stage A chunk kc=1
    {
      const int r0 = t >> 4, cb = t & 15;
      const float* ap = x_inputs + ((size_t)(b0 + r0)*D_ + j)*IN_ + 128 + cb*8;
      #pragma unroll
      for (int pp = 0; pp < 2; ++pp){
        f32x4 v[4];
        #pragma unroll
        for (int p = 0; p < 2; ++p){
          v[p*2]   = *(const f32x4*)(ap + (size_t)(pp*2+p)*16*D_*IN_);
          v[p*2+1] = *(const f32x4*)(ap + (size_t)(pp*2+p)*16*D_*IN_ + 4);
        }
        #pragma unroll
        for (int p = 0; p < 2; ++p){
          const int row = (pp*2+p)*16 + r0;
          u32x4 o;
          o[0] = cvtpk(v[p*2][0],   v[p*2][1]);
          o[1] = cvtpk(v[p*2][2],   v[p*2][3]);
          o[2] = cvtpk(v[p*2+1][0], v[p*2+1][1]);
          o[3] = cvtpk(v[p*2+1][2], v[p*2+1][3]);
          *(u32x4*)(sm + row*256 + ((cb*16) ^ ((row & 7) << 4))) = o;
        }
      }
    }
    __syncthreads();                                   // B3: A1 ready

    // ---- MFMA1 kc=1 ----
    #pragma unroll
    for (int kkl = 0; kkl < 4; ++kkl){
      bf16x8 af[4];
      #pragma unroll
      for (int m = 0; m < 4; ++m){
        const int row = m*16 + l15;
        af[m] = *(const bf16x8*)(sm + row*256 + ((kkl*64 + lg*16) ^ ((row & 7) << 4)));
      }
      #pragma unroll
      for (int m = 0; m < 4; ++m)
        #pragma unroll
        for (int n = 0; n < 3; ++n)
          acc1[m][n] = __builtin_amdgcn_mfma_f32_16x16x32_bf16(af[m], bfr[kkl*3+n], acc1[m][n], 0, 0, 0);
    }

    // ---- G write (lrelu+b1 fused; xdot cols -> f32 side buffers, bf16 zeros into G) ----
    #pragma unroll
    for (int n = 0; n < 3; ++n){
      const int col = wv*48 + n*16 + l15;
      const bool isx  = (col >= 80 && col < 96);
      const bool issx = (col >= 176);
      const float b1v = (isx || issx) ? 0.f : b1pack[j*192 + col];
      #pragma unroll
      for (int m = 0; m < 4; ++m){
        const int row = m*16 + lg*4;
        if (isx){
          #pragma unroll
          for (int e = 0; e < 4; ++e){
            Gx[(row+e)*20 + (col-80)] = acc1[m][n][e];
            G[(row+e)*200 + col] = 0;   // defined zeros (B2T col is zero there)
          }
        } else if (issx){
          #pragma unroll
          for (int e = 0; e < 4; ++e){
            Gsx[(row+e)*20 + (col-176)] = acc1[m][n][e];
            G[(row+e)*200 + col] = 0;
          }
        } else {
          #pragma unroll
          for (int e = 0; e < 4; ++e){
            float v = acc1[m][n][e] + b1v;
            v = fmaxf(v, 0.2f*v);
            G[(row+e)*200 + col] = f2bf(v);
          }
        }
      }
    }
    __syncthreads();                                   // B4: G ready

    // ---- MFMA2: D[k][b] = B2T * G^T, C = xdot + bias (A-frags from regs) ----
    {
      const int brow = wv*16 + l15;
      f32x4 accm = *(const f32x4*)(Gx  + brow*20 + lg*4) + *(const f32x4*)(b2  + j*16 + lg*4);
      f32x4 accs = *(const f32x4*)(Gsx + brow*20 + lg*4) + *(const f32x4*)(sb2 + j*16 + lg*4);
      #pragma unroll
      for (int kk = 0; kk < 3; ++kk){
        bf16x8 g0 = *(const bf16x8*)((char*)G + brow*400       + kk*64 + lg*16);
        bf16x8 g1 = *(const bf16x8*)((char*)G + brow*400 + 192 + kk*64 + lg*16);
        accm = __builtin_amdgcn_mfma_f32_16x16x32_bf16(b2tf[kk],   g0, accm, 0, 0, 0);
        accs = __builtin_amdgcn_mfma_f32_16x16x32_bf16(b2tf[3+kk], g1, accs, 0, 0, 0);
      }

      // ---- E1: nll nodes (lane holds k = lg*4+e for row brow) ----
      const float xv = x_values[(size_t)(b0 + brow)*D_ + j];
      float nn4[4];
      #pragma unroll
      for (int e = 0; e < 4; ++e){
        float mean = accm[e];
        float shv  = accs[e];
        float ex = __expf(-shv);
        float sg = __fdividef(10.f, 1.f + ex);
        float var = fmaxf(sg*sg, 1e-6f);
        float d = xv - mean;
        nn4[e] = 0.5f*(__logf(var) + __fdividef(d*d, var));
      }

      // ---- E2: acc3[q] += sum_k w[j][i][k]*nll[k][b],  i = lg*4+q ----
      #pragma unroll
      for (int g = 0; g < 4; ++g){
        float v0 = nn4[0], v1 = nn4[1], v2 = nn4[2], v3 = nn4[3];
        if (g){
          v0 = __shfl_xor(v0, g<<4); v1 = __shfl_xor(v1, g<<4);
          v2 = __shfl_xor(v2, g<<4); v3 = __shfl_xor(v3, g<<4);
        }
        const int kb = ((lg ^ g) << 2);
        #pragma unroll
        for (int q = 0; q < 4; ++q){
          f32x4 wq = *(const f32x4*)(w_l + (lg*4+q)*16 + kb);
          acc3[q] += wq[0]*v0 + wq[1]*v1 + wq[2]*v2 + wq[3]*v3;
        }
      }
    }
    __syncthreads();                                   // B5: epilogue done
  }

  // final store: partial[jg][b][i], lane covers i = lg*4..lg*4+3 for b = b0+wv*16+l15
  *(f32x4*)(partial + ((size_t)jg*B_TOT + b0 + wv*16 + l15)*16 + lg*4) = acc3;
}

// ---------------- final reduce over 16 j-groups ----------------
__global__ void reduce_kernel(const float* __restrict__ partial, float* __restrict__ out){
  int idx = blockIdx.x*256 + threadIdx.x;   // 131072
  float s = 0.f;
  #pragma unroll
  for (int g = 0; g < 16; ++g) s += partial[(size_t)g*(B_TOT*K_) + idx];
  out[idx] = s;
}

extern "C" void kernel_launch(void* const* d_in, const int* in_sizes, int n_in,
                              void* d_out, int out_size, void* d_ws, size_t ws_size,
                              hipStream_t stream){
  const float* x_values = (const float*)d_in[0];
  const float* x_inputs = (const float*)d_in[1];
  const float* targets  = (const float*)d_in[2];
  const float* W1  = (const float*)d_in[3];
  const float* b1  = (const float*)d_in[4];
  const float* Wh  = (const float*)d_in[5];
  const float* Wx  = (const float*)d_in[6];
  const float* b2  = (const float*)d_in[7];
  const float* sW1 = (const float*)d_in[8];
  const float* sb1 = (const float*)d_in[9];
  const float* sWh = (const float*)d_in[10];
  const float* sWx = (const float*)d_in[11];
  const float* sb2 = (const float*)d_in[12];
  (void)in_sizes; (void)n_in; (void)out_size; (void)ws_size;

  char* ws = (char*)d_ws;
  unsigned short* Wpack2 = (unsigned short*)ws;             // 6,291,456
  float* wsm     = (float*)(ws + 6291456);                  // 65,536
  float* b1pack  = (float*)(ws + 6356992);                  // 49,152
  unsigned short* B2packF = (unsigned short*)(ws + 6406144);// 393,216
  float* partial = (float*)(ws + 6799360);                  // 8,388,608
  float* out = (float*)d_out;

  pack_weights2_kernel<<<dim3(64, 192), 256, 0, stream>>>(W1, Wx, sW1, sWx, Wpack2);
  pack_b1_kernel<<<dim3(64), 192, 0, stream>>>(b1, sb1, b1pack);
  pack_b2f_kernel<<<dim3(64, 3), 256, 0, stream>>>(Wh, sWh, B2packF);
  compute_w_kernel<<<dim3(64), 64, 0, stream>>>(targets, wsm);
  main_kernel<<<dim3(16, 128), 256, 0, stream>>>(x_values, x_inputs, Wpack2, wsm,
                                                 b1pack, B2packF, b2, sb2, partial);
  reduce_kernel<<<dim3(512), 256, 0, stream>>>(partial, out);
}